// Round 4
// baseline (37.174 us; speedup 1.0000x reference)
//
#include <hip/hip_runtime.h>

// out[n,p] = sum_{k=0..7} X[n, p+k] * W[p*8 + k] + b[p],  X zero-padded past P.
// N=1024, P=20000, K=8, LF=1. fp32.
//
// Round-3 lesson: wbase was q0*128; correct is q0*32 (group q owns W[q*32 ..
// q*32+31]). Design unchanged from round 3: coalesced W staging via padded
// LDS, launch_bounds(256,4) so wv[32] stays register-resident, ROWS=8.

constexpr int N  = 1024;
constexpr int P  = 20000;
constexpr int K  = 8;
constexpr int PK = P * K;              // 160000 W floats
constexpr int P4 = P / 4;              // 5000 column-groups of 4
constexpr int COLS_PADDED = 5120;      // 20 blocks of 256 per chunk
constexpr int NCHUNKS = 128;           // row-chunks
constexpr int ROWS = N / NCHUNKS;      // 8 rows per thread

constexpr int TILE_W_FLOATS = 256 * 32;                      // 8192
constexpr int LDS_FLOATS = TILE_W_FLOATS + TILE_W_FLOATS/32; // 8448 (pad 1/32)

__device__ __forceinline__ int pad_idx(int l) { return l + (l >> 5); }

__global__ __launch_bounds__(256, 4)
void local_linear_kernel(const float* __restrict__ X,
                         const float* __restrict__ W,
                         const float* __restrict__ b,
                         float* __restrict__ out) {
    __shared__ float wsh[LDS_FLOATS];

    const int t     = threadIdx.x;
    const int tid   = blockIdx.x * blockDim.x + t;
    const int chunk = tid / COLS_PADDED;          // block-uniform (5120%256==0)
    const int q     = tid - chunk * COLS_PADDED;  // column-group index
    const int q0    = q - t;                      // block's first column-group
    const int p     = q * 4;
    const int n0    = chunk * ROWS;

    // ---- coalesced W tile staging: floats [q0*32, q0*32 + 8192) ----
    const int wbase = q0 * 32;                    // group q owns W[32q..32q+31]
    #pragma unroll
    for (int i = 0; i < 8; ++i) {
        int c    = t + 256 * i;                   // float4 chunk in tile
        int gidx = wbase + 4 * c;
        float4 w4 = make_float4(0.f, 0.f, 0.f, 0.f);
        if (gidx + 3 < PK)                        // last blocks of chunk only
            w4 = *reinterpret_cast<const float4*>(W + gidx);
        int l = 4 * c;                            // float4 never straddles a pad
        int ph = pad_idx(l);
        wsh[ph + 0] = w4.x;
        wsh[ph + 1] = w4.y;
        wsh[ph + 2] = w4.z;
        wsh[ph + 3] = w4.w;
    }
    __syncthreads();

    if (q >= P4) return;                          // padding lanes

    // ---- LDS -> registers: my 32 W floats (33t+j -> bank (t+j)%32) ----
    float wv[32];
    #pragma unroll
    for (int j = 0; j < 32; ++j)
        wv[j] = wsh[33 * t + j];

    const float4 bv = *reinterpret_cast<const float4*>(b + p);
    const bool interior = (p + 12 <= P);

    // ---- row loop: pure coalesced traffic ----
    #pragma unroll 2
    for (int r = 0; r < ROWS; ++r) {
        const float* xrow = X + (size_t)(n0 + r) * P;

        float xv[12];
        if (interior) {
            float4 a = *reinterpret_cast<const float4*>(xrow + p);
            float4 c = *reinterpret_cast<const float4*>(xrow + p + 4);
            float4 d = *reinterpret_cast<const float4*>(xrow + p + 8);
            xv[0] = a.x; xv[1] = a.y; xv[2]  = a.z; xv[3]  = a.w;
            xv[4] = c.x; xv[5] = c.y; xv[6]  = c.z; xv[7]  = c.w;
            xv[8] = d.x; xv[9] = d.y; xv[10] = d.z; xv[11] = d.w;
        } else {
            #pragma unroll
            for (int i = 0; i < 12; ++i)
                xv[i] = (p + i < P) ? xrow[p + i] : 0.0f;   // matches jnp.pad
        }

        float r0 = bv.x, r1 = bv.y, r2 = bv.z, r3 = bv.w;
        #pragma unroll
        for (int k = 0; k < K; ++k) {
            r0 += xv[0 + k] * wv[0  + k];
            r1 += xv[1 + k] * wv[8  + k];
            r2 += xv[2 + k] * wv[16 + k];
            r3 += xv[3 + k] * wv[24 + k];
        }

        float4 o; o.x = r0; o.y = r1; o.z = r2; o.w = r3;
        *reinterpret_cast<float4*>(out + (size_t)(n0 + r) * P + p) = o;
    }
}

extern "C" void kernel_launch(void* const* d_in, const int* in_sizes, int n_in,
                              void* d_out, int out_size, void* d_ws, size_t ws_size,
                              hipStream_t stream) {
    const float* X = (const float*)d_in[0];
    const float* W = (const float*)d_in[1];
    const float* b = (const float*)d_in[2];
    float* out = (float*)d_out;

    constexpr int total_threads = COLS_PADDED * NCHUNKS;  // 655,360
    constexpr int block = 256;
    constexpr int grid = total_threads / block;           // 2,560 blocks

    local_linear_kernel<<<grid, block, 0, stream>>>(X, W, b, out);
}